// Round 22
// baseline (736.487 us; speedup 1.0000x reference)
//
#include <hip/hip_runtime.h>

// B=16, N=8192, C1=64, C2=128, C3=256, NP=32
// Bit-replication of numpy fp32 reference: sequential accumulation, ascending
// contraction index, NO FMA (__fmul_rn/__fadd_rn), correctly-rounded sqrt/div,
// top-k ties -> lower index. DO NOT introduce FMA/fp64 — ordering breaks.
// RULE: never runtime-index a register array (round-5 spill: 674->2350us).
// RULE: occupancy first — >= ~4 waves/SIMD (round-7: 2 waves/SIMD -> 32% VALU).
// RULE: v_pk_*_f32 via inline asm is NOT bit-identical (round-9). Scalar only.
// RULE: per-thread acc arrays > ~16 get AGPR-allocated -> accvgpr round-trips
//       (round-8: 1.8x VALU floor). Keep acc <= 16 per thread.
// RULE: block-wide multi-pass argmax is barrier-bound (round-12: 262us).
// RULE: do NOT hand-prefetch an already-pipelined loop (round-15 regress).
// RULE: sibling blocks sharing data -> same XCD via blockIdx%8 (round-16).
// RULE: LDS hot reads must be lane-consecutive (round-18 gather transpose;
//       round-21: LDS-staged gather rows -28us — random 4B global gathers
//       split into per-lane L1 transactions).
// RULE: uniform weight streams must be CONTIGUOUS in consumption order
//       (round-20: w3 transposed -> mlp3 147->133us).
// RULE: candidate+refine restructure is a net loss (round-19: +82us).
// THIS ROUND: fuse mlp12+mlp3 via 32KB LDS h2 tile (block = 64 points).
//       Removes 67MB h2g write + 67MB read + 1 launch. Per-output fp32 op
//       order copied verbatim -> h bit-identical.

using v4f = __attribute__((ext_vector_type(4))) float;

__device__ __forceinline__ float bf16rne(float x) {
    unsigned u = __float_as_uint(x);
    u = (u + 0x7FFFu + ((u >> 16) & 1u)) & 0xFFFF0000u;
    return __uint_as_float(u);
}

// ---------------- scales: s = g / sqrt(v + 1e-5f), exact fp32 ----------------
__global__ void scales_kernel(const float* __restrict__ g1, const float* __restrict__ v1,
                              const float* __restrict__ g2, const float* __restrict__ v2,
                              const float* __restrict__ g3, const float* __restrict__ v3,
                              float* __restrict__ s) {
    int t = threadIdx.x;
    if (t < 64)       s[t] = __fdiv_rn(g1[t],       __fsqrt_rn(__fadd_rn(v1[t],       1e-5f)));
    else if (t < 192) s[t] = __fdiv_rn(g2[t - 64],  __fsqrt_rn(__fadd_rn(v2[t - 64],  1e-5f)));
    else if (t < 448) s[t] = __fdiv_rn(g3[t - 192], __fsqrt_rn(__fadd_rn(v3[t - 192], 1e-5f)));
}

// ---------------- w3 transpose: contiguous per-(q,tile) weight runs ----------------
__global__ void w3t_kernel(const float* __restrict__ w3, float* __restrict__ w3t) {
    int i = blockIdx.x * 256 + threadIdx.x;    // 32768 = 256 ch * 128 k
    int o = i >> 7, k = i & 127;
    int q = k >> 2, c = k & 3;
    int tile = o >> 4, j = o & 15;
    w3t[(((q * 16 + tile) * 16 + j) << 2) + c] = w3[o * 128 + k];
}

// ---------------- fused MLP (EXACT): x -> h[16,256,8192]; h2 in LDS ----------------
// block = 64 points x 256 threads. thread: pt_l = t&63 (lane), quarter = t>>6.
// Phase A: layer1 (own pt, full h1) + layer2 (quarter's 32 ch) -> LDS [q][pt].
// Phase B: 4 passes x 4 tiles x 4 ch (acc[16]); h2 read per-wave contiguous.
__global__ __launch_bounds__(256, 1) void mlpf_kernel(
        const float* __restrict__ x,
        const float* __restrict__ w1, const float* __restrict__ b1,
        const float* __restrict__ m1, const float* __restrict__ be1,
        const float* __restrict__ w2, const float* __restrict__ b2,
        const float* __restrict__ m2, const float* __restrict__ be2,
        const float* __restrict__ w3t, const float* __restrict__ b3,
        const float* __restrict__ m3, const float* __restrict__ be3,
        const float* __restrict__ sc,
        float* __restrict__ h) {
    __shared__ v4f h2s[2048];                  // [q][pt] = [32][64], 32 KB

    const float* s1 = sc;
    const float* s2 = sc + 64;
    const float* s3 = sc + 192;

    int t       = threadIdx.x;
    int pt_l    = t & 63;
    int quarter = t >> 6;
    int pt      = blockIdx.x * 64 + pt_l;
    int b       = pt >> 13;
    int n       = pt & 8191;

    // ----- layer 1 (exact, verbatim) -----
    const float* xb = x + (size_t)b * 24576 + n;
    float x0 = xb[0], x1 = xb[8192], x2 = xb[16384];

    float h1[64];
#pragma unroll
    for (int o = 0; o < 64; ++o) {
        float acc = __fmul_rn(w1[o * 3 + 0], x0);
        acc = __fadd_rn(acc, __fmul_rn(w1[o * 3 + 1], x1));
        acc = __fadd_rn(acc, __fmul_rn(w1[o * 3 + 2], x2));
        float hpb = __fadd_rn(acc, b1[o]);
        float tt  = __fsub_rn(hpb, m1[o]);
        float r   = __fadd_rn(__fmul_rn(tt, s1[o]), be1[o]);
        h1[o] = fmaxf(r, 0.0f);
    }

    // ----- layer 2 (exact, verbatim body): quarter's 32 channels -> LDS -----
    const v4f* w2v = (const v4f*)w2;
    for (int qq = 0; qq < 8; ++qq) {
        int q = quarter * 8 + qq;
        v4f hv;
#pragma unroll
        for (int j = 0; j < 4; ++j) {
            int c2 = q * 4 + j;
            const v4f* wr = w2v + c2 * 16;
            float a = 0.0f;
#pragma unroll
            for (int k = 0; k < 16; ++k) {
                v4f w = wr[k];
                a = __fadd_rn(a, __fmul_rn(w.x, h1[4 * k + 0]));
                a = __fadd_rn(a, __fmul_rn(w.y, h1[4 * k + 1]));
                a = __fadd_rn(a, __fmul_rn(w.z, h1[4 * k + 2]));
                a = __fadd_rn(a, __fmul_rn(w.w, h1[4 * k + 3]));
            }
            float hpb = __fadd_rn(a, b2[c2]);
            float tt  = __fsub_rn(hpb, m2[c2]);
            hv[j] = fmaxf(__fadd_rn(__fmul_rn(tt, s2[c2]), be2[c2]), 0.0f);
        }
        h2s[q * 64 + pt_l] = hv;               // per-wave contiguous write
    }
    __syncthreads();

    // ----- layer 3 (exact op order): 4 passes x (4 tiles x 4 ch), acc[16] -----
    const v4f* w3tv = (const v4f*)w3t;         // [(q*16+tile)*16 + j]
    float* hb = h + (size_t)b * 2097152 + n;

    for (int tp = 0; tp < 4; ++tp) {
        float acc[16];
#pragma unroll
        for (int j = 0; j < 16; ++j) acc[j] = 0.0f;

        for (int q = 0; q < 32; ++q) {
            v4f hv = h2s[q * 64 + pt_l];       // per-wave contiguous read
            const v4f* wq = w3tv + (size_t)(q * 16 + tp * 4) * 16 + quarter * 4;
#pragma unroll
            for (int c = 0; c < 4; ++c) {      // tile = tp*4 + c
                const v4f* wt = wq + c * 16;
#pragma unroll
                for (int jj = 0; jj < 4; ++jj) {
                    v4f w = wt[jj];
                    acc[c * 4 + jj] = __fadd_rn(acc[c * 4 + jj], __fmul_rn(w.x, hv.x));
                    acc[c * 4 + jj] = __fadd_rn(acc[c * 4 + jj], __fmul_rn(w.y, hv.y));
                    acc[c * 4 + jj] = __fadd_rn(acc[c * 4 + jj], __fmul_rn(w.z, hv.z));
                    acc[c * 4 + jj] = __fadd_rn(acc[c * 4 + jj], __fmul_rn(w.w, hv.w));
                }
            }
        }

#pragma unroll
        for (int c = 0; c < 4; ++c) {
#pragma unroll
            for (int jj = 0; jj < 4; ++jj) {
                int o = (tp * 4 + c) * 16 + quarter * 4 + jj;
                float hpb = __fadd_rn(acc[c * 4 + jj], b3[o]);
                float tt  = __fsub_rn(hpb, m3[o]);
                float rr  = __fadd_rn(__fmul_rn(tt, s3[o]), be3[o]);
                hb[(size_t)o * 8192] = rr;
            }
        }
    }
}

// ---------------- top-32 per row: 2 waves/row scan + LDS merge + wave pop ----------------
__global__ __launch_bounds__(256) void topk_kernel(const float* __restrict__ h,
                                                   int* __restrict__ idx_out) {
    __shared__ unsigned long long mrg[2][64][4];

    int t      = threadIdx.x;
    int lane   = t & 63;
    int waveid = (t >> 6) & 1;
    int rhalf  = t >> 7;                       // row within block
    int row    = blockIdx.x * 2 + rhalf;
    const float* hr = h + (size_t)row * 8192;
    const v4f* hv4  = (const v4f*)hr;

    unsigned long long k0 = 0, k1 = 0, k2 = 0, k3 = 0;   // sorted desc
    int j0 = waveid * 16;
    int lanebase = 8191 - lane * 4;

    v4f p0 = hv4[(j0 + 0) * 64 + lane], p1 = hv4[(j0 + 1) * 64 + lane];
    v4f p2 = hv4[(j0 + 2) * 64 + lane], p3 = hv4[(j0 + 3) * 64 + lane];

    for (int jb = 0; jb < 4; ++jb) {
        int jn = j0 + ((jb < 3) ? (jb + 1) * 4 : 0);     // clamped prefetch
        v4f n0 = hv4[(jn + 0) * 64 + lane], n1 = hv4[(jn + 1) * 64 + lane];
        v4f n2 = hv4[(jn + 2) * 64 + lane], n3 = hv4[(jn + 3) * 64 + lane];

#pragma unroll
        for (int jj = 0; jj < 4; ++jj) {
            v4f v = (jj == 0) ? p0 : (jj == 1) ? p1 : (jj == 2) ? p2 : p3;
            int j = j0 + jb * 4 + jj;
#pragma unroll
            for (int c = 0; c < 4; ++c) {
                unsigned u = __float_as_uint(v[c]);
                u = (u & 0x80000000u) ? ~u : (u | 0x80000000u);
                unsigned long long key =
                    ((unsigned long long)u << 13) |
                    (unsigned)(lanebase - (j * 256 + c));
                unsigned long long s = key, hi;
                hi = (k0 > s) ? k0 : s;  s = (k0 > s) ? s : k0;  k0 = hi;
                hi = (k1 > s) ? k1 : s;  s = (k1 > s) ? s : k1;  k1 = hi;
                hi = (k2 > s) ? k2 : s;  s = (k2 > s) ? s : k2;  k2 = hi;
                k3 = (k3 > s) ? k3 : s;
            }
        }
        p0 = n0; p1 = n1; p2 = n2; p3 = n3;
    }

    if (waveid == 1) {
        mrg[rhalf][lane][0] = k0; mrg[rhalf][lane][1] = k1;
        mrg[rhalf][lane][2] = k2; mrg[rhalf][lane][3] = k3;
    }
    __syncthreads();
    if (waveid == 1) return;

#pragma unroll
    for (int q = 0; q < 4; ++q) {
        unsigned long long s = mrg[rhalf][lane][q], hi;
        hi = (k0 > s) ? k0 : s;  s = (k0 > s) ? s : k0;  k0 = hi;
        hi = (k1 > s) ? k1 : s;  s = (k1 > s) ? s : k1;  k1 = hi;
        hi = (k2 > s) ? k2 : s;  s = (k2 > s) ? s : k2;  k2 = hi;
        k3 = (k3 > s) ? k3 : s;
    }

    unsigned long long last = 0xFFFFFFFFFFFFFFFFull;
    int valid = 4;

    for (int pass = 0; pass < 32; ++pass) {
        unsigned long long m = k0;
#pragma unroll
        for (int s = 1; s < 64; s <<= 1) {
            unsigned long long o = __shfl_xor(m, s, 64);
            m = (o > m) ? o : m;
        }
        if (lane == 0) idx_out[row * 32 + pass] = 8191 - (int)(m & 8191ull);

        if (k0 == m) {                 // unique winner (index embedded)
            last = m;
            k0 = k1; k1 = k2; k2 = k3; k3 = 0ull;
            --valid;
            if (valid == 0 && pass < 31) {
                // refill: all remaining own-subset keys are strictly < last (rare)
                for (int j = 0; j < 32; ++j) {
                    v4f v = *(const v4f*)&hr[j * 256 + lane * 4];
#pragma unroll
                    for (int c = 0; c < 4; ++c) {
                        unsigned u = __float_as_uint(v[c]);
                        u = (u & 0x80000000u) ? ~u : (u | 0x80000000u);
                        int i = j * 256 + lane * 4 + c;
                        unsigned long long key = ((unsigned long long)u << 13) | (unsigned)(8191 - i);
                        if (key < last && key > k3) {
                            unsigned long long s = key, hi;
                            hi = (k0 > s) ? k0 : s;  s = (k0 > s) ? s : k0;  k0 = hi;
                            hi = (k1 > s) ? k1 : s;  s = (k1 > s) ? s : k1;  k1 = hi;
                            hi = (k2 > s) ? k2 : s;  s = (k2 > s) ? s : k2;  k2 = hi;
                            k3 = s;
                        }
                    }
                }
                valid = 4;   // zero-keys never win a pass, so overcount is safe
            }
        }
    }
}

// ---------------- gather: LDS-staged rows; random reads hit LDS not L1 ----------------
__global__ __launch_bounds__(256) void gather_kernel(const float* __restrict__ h,
                                                     const int* __restrict__ idx,
                                                     float* __restrict__ out) {
    __shared__ int   idxs2[8192];   // 32 KB: idxs2[k*256+cs]
    __shared__ float hlds[8192];    // 32 KB: one h row

    int blk = blockIdx.x;
    int b   = blk >> 6;
    int cfq = blk & 63;
    int t   = threadIdx.x;

    for (int d = t; d < 8192; d += 256) {
        int k = d >> 8, cs = d & 255;
        idxs2[d] = idx[b * 8192 + cs * 32 + k];
    }

    const float* hb = h + (size_t)b * 2097152;
    float* ob = out + (size_t)b * 2097152;

#pragma unroll
    for (int r = 0; r < 4; ++r) {
        int cf = cfq * 4 + r;
        const float* hrow = hb + (size_t)cf * 8192;
        float* orow = ob + (size_t)cf * 8192;

        const v4f* hr4 = (const v4f*)hrow;
#pragma unroll
        for (int s = 0; s < 8; ++s) {
            v4f v = hr4[s * 256 + t];
            *(v4f*)&hlds[(s * 256 + t) * 4] = v;
        }
        __syncthreads();

#pragma unroll 8
        for (int rep = 0; rep < 32; ++rep) {
            int elem = rep * 256 + t;
            int i = idxs2[elem];
            orow[elem] = bf16rne(hlds[i]);
        }
        __syncthreads();
    }
}

extern "C" void kernel_launch(void* const* d_in, const int* in_sizes, int n_in,
                              void* d_out, int out_size, void* d_ws, size_t ws_size,
                              hipStream_t stream) {
    const float* x   = (const float*)d_in[0];
    const float* w1  = (const float*)d_in[1];
    const float* b1  = (const float*)d_in[2];
    const float* g1  = (const float*)d_in[3];
    const float* be1 = (const float*)d_in[4];
    const float* m1  = (const float*)d_in[5];
    const float* v1  = (const float*)d_in[6];
    const float* w2  = (const float*)d_in[7];
    const float* b2  = (const float*)d_in[8];
    const float* g2  = (const float*)d_in[9];
    const float* be2 = (const float*)d_in[10];
    const float* m2  = (const float*)d_in[11];
    const float* v2  = (const float*)d_in[12];
    const float* w3  = (const float*)d_in[13];
    const float* b3  = (const float*)d_in[14];
    const float* g3  = (const float*)d_in[15];
    const float* be3 = (const float*)d_in[16];
    const float* m3  = (const float*)d_in[17];
    const float* v3  = (const float*)d_in[18];

    char* ws = (char*)d_ws;
    float* h    = (float*)(ws);                  // 134,217,728 B
    int*   idxb = (int*)(ws + 134217728);        //     524,288 B
    float* sc   = (float*)(ws + 134742016);      //       1,792 B
    float* w3t  = (float*)(ws + 134744064);      //     131,072 B

    scales_kernel<<<1, 448, 0, stream>>>(g1, v1, g2, v2, g3, v3, sc);
    w3t_kernel<<<128, 256, 0, stream>>>(w3, w3t);
    mlpf_kernel<<<2048, 256, 0, stream>>>(x, w1, b1, m1, be1,
                                          w2, b2, m2, be2,
                                          w3t, b3, m3, be3, sc, h);
    topk_kernel<<<2048, 256, 0, stream>>>(h, idxb);
    gather_kernel<<<1024, 256, 0, stream>>>(h, idxb, (float*)d_out);
}

// Round 23
// 276.862 us; speedup vs baseline: 2.6601x; 2.6601x over previous
//
#include <hip/hip_runtime.h>

// B=16, N=8192, C1=64, C2=128, C3=256, NP=32
// Bit-replication of numpy fp32 reference: sequential accumulation, ascending
// contraction index, NO FMA (__fmul_rn/__fadd_rn), correctly-rounded sqrt/div,
// top-k ties -> lower index. DO NOT introduce FMA/fp64 — ordering breaks.
// RULE: never runtime-index a register array (round-5 spill: 674->2350us).
// RULE: occupancy first — grid >= ~2048 blocks of 256 (round-7 lesson).
// RULE: v_pk_*_f32 via inline asm is NOT bit-identical (round-9). Scalar only.
// RULE: per-thread acc arrays > ~16 get AGPR-allocated -> accvgpr round-trips
//       (round-8: 1.8x VALU floor). Keep acc <= 16 per thread.
// RULE: block-wide multi-pass argmax is barrier-bound (round-12: 262us).
// RULE: do NOT hand-prefetch an already-pipelined loop (round-15 regress).
// RULE: sibling blocks sharing data -> same XCD via blockIdx%8 (round-16).
// RULE: LDS hot reads must be lane-consecutive (round-18); LDS-stage rows
//       for random gathers (round-21: -28us, L1 transaction splits).
// RULE: uniform weight streams must be CONTIGUOUS in consumption order
//       (round-20: w3 transposed -> mlp3 147->133us).
// RULE: candidate+refine restructure is a net loss (round-19: +82us).
// RULE: do NOT fuse MLP stages through an LDS tile (round-22: 668us vs 175;
//       32KB tile -> 2.6 blocks/CU, latency unhidden; fusion trades traffic
//       (not the bottleneck) for occupancy (the bottleneck)).
// STATUS: mlp3 at 1.22x structural no-FMA issue floor (FMA/prefetch/fusion
//       all confirmed envelope); composite ~278us is the practical floor.

using v4f = __attribute__((ext_vector_type(4))) float;

__device__ __forceinline__ float bf16rne(float x) {
    unsigned u = __float_as_uint(x);
    u = (u + 0x7FFFu + ((u >> 16) & 1u)) & 0xFFFF0000u;
    return __uint_as_float(u);
}

// ---------------- scales: s = g / sqrt(v + 1e-5f), exact fp32 ----------------
__global__ void scales_kernel(const float* __restrict__ g1, const float* __restrict__ v1,
                              const float* __restrict__ g2, const float* __restrict__ v2,
                              const float* __restrict__ g3, const float* __restrict__ v3,
                              float* __restrict__ s) {
    int t = threadIdx.x;
    if (t < 64)       s[t] = __fdiv_rn(g1[t],       __fsqrt_rn(__fadd_rn(v1[t],       1e-5f)));
    else if (t < 192) s[t] = __fdiv_rn(g2[t - 64],  __fsqrt_rn(__fadd_rn(v2[t - 64],  1e-5f)));
    else if (t < 448) s[t] = __fdiv_rn(g3[t - 192], __fsqrt_rn(__fadd_rn(v3[t - 192], 1e-5f)));
}

// ---------------- w3 transpose: contiguous per-(q,tile) weight runs ----------------
__global__ void w3t_kernel(const float* __restrict__ w3, float* __restrict__ w3t) {
    int i = blockIdx.x * 256 + threadIdx.x;    // 32768 = 256 ch * 128 k
    int o = i >> 7, k = i & 127;
    int q = k >> 2, c = k & 3;
    int tile = o >> 4, j = o & 15;
    w3t[(((q * 16 + tile) * 16 + j) << 2) + c] = w3[o * 128 + k];
}

// ---------------- layers 1+2 (EXACT): x -> h2q[32][131072] float4 (in d_out) ----------
__global__ __launch_bounds__(256, 1) void mlp12_kernel(
        const float* __restrict__ x,
        const float* __restrict__ w1, const float* __restrict__ b1,
        const float* __restrict__ m1, const float* __restrict__ be1,
        const float* __restrict__ w2, const float* __restrict__ b2,
        const float* __restrict__ m2, const float* __restrict__ be2,
        const float* __restrict__ sc,
        float* __restrict__ h2g) {
    const float* s1 = sc;
    const float* s2 = sc + 64;

    int t    = threadIdx.x;
    int tile = blockIdx.x & 3;                 // c2 quarter
    int pt   = (blockIdx.x >> 2) * 256 + t;
    int b    = pt >> 13;
    int n    = pt & 8191;

    const float* xb = x + (size_t)b * 24576 + n;
    float x0 = xb[0], x1 = xb[8192], x2 = xb[16384];

    float h1[64];
#pragma unroll
    for (int o = 0; o < 64; ++o) {
        float acc = __fmul_rn(w1[o * 3 + 0], x0);
        acc = __fadd_rn(acc, __fmul_rn(w1[o * 3 + 1], x1));
        acc = __fadd_rn(acc, __fmul_rn(w1[o * 3 + 2], x2));
        float hpb = __fadd_rn(acc, b1[o]);
        float tt  = __fsub_rn(hpb, m1[o]);
        float r   = __fadd_rn(__fmul_rn(tt, s1[o]), be1[o]);
        h1[o] = fmaxf(r, 0.0f);
    }

    v4f* dst = (v4f*)h2g;
    const v4f* w2v = (const v4f*)w2;
    for (int qq = 0; qq < 8; ++qq) {
        int q = tile * 8 + qq;
        v4f hv;
#pragma unroll
        for (int j = 0; j < 4; ++j) {
            int c2 = q * 4 + j;
            const v4f* wr = w2v + c2 * 16;
            float a = 0.0f;
#pragma unroll
            for (int k = 0; k < 16; ++k) {
                v4f w = wr[k];
                a = __fadd_rn(a, __fmul_rn(w.x, h1[4 * k + 0]));
                a = __fadd_rn(a, __fmul_rn(w.y, h1[4 * k + 1]));
                a = __fadd_rn(a, __fmul_rn(w.z, h1[4 * k + 2]));
                a = __fadd_rn(a, __fmul_rn(w.w, h1[4 * k + 3]));
            }
            float hpb = __fadd_rn(a, b2[c2]);
            float tt  = __fsub_rn(hpb, m2[c2]);
            hv[j] = fmaxf(__fadd_rn(__fmul_rn(tt, s2[c2]), be2[c2]), 0.0f);
        }
        dst[(size_t)q * 131072 + pt] = hv;
    }
}

// ---------------- layer 3 (EXACT): h2q -> h; 16 ch/thread; contiguous weights ----------
__global__ __launch_bounds__(256) void mlp3_kernel(
        const float* __restrict__ h2g,
        const float* __restrict__ w3t, const float* __restrict__ b3,
        const float* __restrict__ m3, const float* __restrict__ be3,
        const float* __restrict__ sc,
        float* __restrict__ h) {
    const float* s3 = sc + 192;

    int B    = blockIdx.x;
    int xcd  = B & 7;
    int slot = B >> 3;
    int tile = slot & 15;                      // out-channel 16-tile
    int ptb  = (slot >> 4) * 8 + xcd;          // [0,512)
    int t    = threadIdx.x;
    int pt   = ptb * 256 + t;
    int b    = pt >> 13;
    int n    = pt & 8191;
    int ob   = tile * 16;

    float acc[16];
#pragma unroll
    for (int j = 0; j < 16; ++j) acc[j] = 0.0f;

    const v4f* src  = (const v4f*)h2g;
    const v4f* w3tv = (const v4f*)w3t;         // [(q*16+tile)*16 + j]

    for (int q = 0; q < 32; ++q) {
        v4f hv = src[(size_t)q * 131072 + pt];
        const v4f* wq = w3tv + (size_t)(q * 16 + tile) * 16;   // 256B contiguous
#pragma unroll
        for (int j = 0; j < 16; ++j) {
            v4f w = wq[j];
            acc[j] = __fadd_rn(acc[j], __fmul_rn(w.x, hv.x));
            acc[j] = __fadd_rn(acc[j], __fmul_rn(w.y, hv.y));
            acc[j] = __fadd_rn(acc[j], __fmul_rn(w.z, hv.z));
            acc[j] = __fadd_rn(acc[j], __fmul_rn(w.w, hv.w));
        }
    }

    float* hb = h + (size_t)b * 2097152 + n;
#pragma unroll
    for (int j = 0; j < 16; ++j) {
        int o = ob + j;
        float hpb = __fadd_rn(acc[j], b3[o]);
        float tt  = __fsub_rn(hpb, m3[o]);
        float rr  = __fadd_rn(__fmul_rn(tt, s3[o]), be3[o]);
        hb[(size_t)o * 8192] = rr;
    }
}

// ---------------- top-32 per row: 2 waves/row scan + LDS merge + wave pop ----------------
__global__ __launch_bounds__(256) void topk_kernel(const float* __restrict__ h,
                                                   int* __restrict__ idx_out) {
    __shared__ unsigned long long mrg[2][64][4];

    int t      = threadIdx.x;
    int lane   = t & 63;
    int waveid = (t >> 6) & 1;
    int rhalf  = t >> 7;                       // row within block
    int row    = blockIdx.x * 2 + rhalf;
    const float* hr = h + (size_t)row * 8192;
    const v4f* hv4  = (const v4f*)hr;

    unsigned long long k0 = 0, k1 = 0, k2 = 0, k3 = 0;   // sorted desc
    int j0 = waveid * 16;
    int lanebase = 8191 - lane * 4;

    v4f p0 = hv4[(j0 + 0) * 64 + lane], p1 = hv4[(j0 + 1) * 64 + lane];
    v4f p2 = hv4[(j0 + 2) * 64 + lane], p3 = hv4[(j0 + 3) * 64 + lane];

    for (int jb = 0; jb < 4; ++jb) {
        int jn = j0 + ((jb < 3) ? (jb + 1) * 4 : 0);     // clamped prefetch
        v4f n0 = hv4[(jn + 0) * 64 + lane], n1 = hv4[(jn + 1) * 64 + lane];
        v4f n2 = hv4[(jn + 2) * 64 + lane], n3 = hv4[(jn + 3) * 64 + lane];

#pragma unroll
        for (int jj = 0; jj < 4; ++jj) {
            v4f v = (jj == 0) ? p0 : (jj == 1) ? p1 : (jj == 2) ? p2 : p3;
            int j = j0 + jb * 4 + jj;
#pragma unroll
            for (int c = 0; c < 4; ++c) {
                unsigned u = __float_as_uint(v[c]);
                u = (u & 0x80000000u) ? ~u : (u | 0x80000000u);
                unsigned long long key =
                    ((unsigned long long)u << 13) |
                    (unsigned)(lanebase - (j * 256 + c));
                unsigned long long s = key, hi;
                hi = (k0 > s) ? k0 : s;  s = (k0 > s) ? s : k0;  k0 = hi;
                hi = (k1 > s) ? k1 : s;  s = (k1 > s) ? s : k1;  k1 = hi;
                hi = (k2 > s) ? k2 : s;  s = (k2 > s) ? s : k2;  k2 = hi;
                k3 = (k3 > s) ? k3 : s;
            }
        }
        p0 = n0; p1 = n1; p2 = n2; p3 = n3;
    }

    if (waveid == 1) {
        mrg[rhalf][lane][0] = k0; mrg[rhalf][lane][1] = k1;
        mrg[rhalf][lane][2] = k2; mrg[rhalf][lane][3] = k3;
    }
    __syncthreads();
    if (waveid == 1) return;

#pragma unroll
    for (int q = 0; q < 4; ++q) {
        unsigned long long s = mrg[rhalf][lane][q], hi;
        hi = (k0 > s) ? k0 : s;  s = (k0 > s) ? s : k0;  k0 = hi;
        hi = (k1 > s) ? k1 : s;  s = (k1 > s) ? s : k1;  k1 = hi;
        hi = (k2 > s) ? k2 : s;  s = (k2 > s) ? s : k2;  k2 = hi;
        k3 = (k3 > s) ? k3 : s;
    }

    unsigned long long last = 0xFFFFFFFFFFFFFFFFull;
    int valid = 4;

    for (int pass = 0; pass < 32; ++pass) {
        unsigned long long m = k0;
#pragma unroll
        for (int s = 1; s < 64; s <<= 1) {
            unsigned long long o = __shfl_xor(m, s, 64);
            m = (o > m) ? o : m;
        }
        if (lane == 0) idx_out[row * 32 + pass] = 8191 - (int)(m & 8191ull);

        if (k0 == m) {                 // unique winner (index embedded)
            last = m;
            k0 = k1; k1 = k2; k2 = k3; k3 = 0ull;
            --valid;
            if (valid == 0 && pass < 31) {
                // refill: all remaining own-subset keys are strictly < last (rare)
                for (int j = 0; j < 32; ++j) {
                    v4f v = *(const v4f*)&hr[j * 256 + lane * 4];
#pragma unroll
                    for (int c = 0; c < 4; ++c) {
                        unsigned u = __float_as_uint(v[c]);
                        u = (u & 0x80000000u) ? ~u : (u | 0x80000000u);
                        int i = j * 256 + lane * 4 + c;
                        unsigned long long key = ((unsigned long long)u << 13) | (unsigned)(8191 - i);
                        if (key < last && key > k3) {
                            unsigned long long s = key, hi;
                            hi = (k0 > s) ? k0 : s;  s = (k0 > s) ? s : k0;  k0 = hi;
                            hi = (k1 > s) ? k1 : s;  s = (k1 > s) ? s : k1;  k1 = hi;
                            hi = (k2 > s) ? k2 : s;  s = (k2 > s) ? s : k2;  k2 = hi;
                            k3 = s;
                        }
                    }
                }
                valid = 4;   // zero-keys never win a pass, so overcount is safe
            }
        }
    }
}

// ---------------- gather: LDS-staged rows; random reads hit LDS not L1 ----------------
__global__ __launch_bounds__(256) void gather_kernel(const float* __restrict__ h,
                                                     const int* __restrict__ idx,
                                                     float* __restrict__ out) {
    __shared__ int   idxs2[8192];   // 32 KB: idxs2[k*256+cs]
    __shared__ float hlds[8192];    // 32 KB: one h row

    int blk = blockIdx.x;
    int b   = blk >> 6;
    int cfq = blk & 63;
    int t   = threadIdx.x;

    for (int d = t; d < 8192; d += 256) {
        int k = d >> 8, cs = d & 255;
        idxs2[d] = idx[b * 8192 + cs * 32 + k];
    }

    const float* hb = h + (size_t)b * 2097152;
    float* ob = out + (size_t)b * 2097152;

#pragma unroll
    for (int r = 0; r < 4; ++r) {
        int cf = cfq * 4 + r;
        const float* hrow = hb + (size_t)cf * 8192;
        float* orow = ob + (size_t)cf * 8192;

        const v4f* hr4 = (const v4f*)hrow;
#pragma unroll
        for (int s = 0; s < 8; ++s) {
            v4f v = hr4[s * 256 + t];
            *(v4f*)&hlds[(s * 256 + t) * 4] = v;
        }
        __syncthreads();

#pragma unroll 8
        for (int rep = 0; rep < 32; ++rep) {
            int elem = rep * 256 + t;
            int i = idxs2[elem];
            orow[elem] = bf16rne(hlds[i]);
        }
        __syncthreads();
    }
}

extern "C" void kernel_launch(void* const* d_in, const int* in_sizes, int n_in,
                              void* d_out, int out_size, void* d_ws, size_t ws_size,
                              hipStream_t stream) {
    const float* x   = (const float*)d_in[0];
    const float* w1  = (const float*)d_in[1];
    const float* b1  = (const float*)d_in[2];
    const float* g1  = (const float*)d_in[3];
    const float* be1 = (const float*)d_in[4];
    const float* m1  = (const float*)d_in[5];
    const float* v1  = (const float*)d_in[6];
    const float* w2  = (const float*)d_in[7];
    const float* b2  = (const float*)d_in[8];
    const float* g2  = (const float*)d_in[9];
    const float* be2 = (const float*)d_in[10];
    const float* m2  = (const float*)d_in[11];
    const float* v2  = (const float*)d_in[12];
    const float* w3  = (const float*)d_in[13];
    const float* b3  = (const float*)d_in[14];
    const float* g3  = (const float*)d_in[15];
    const float* be3 = (const float*)d_in[16];
    const float* m3  = (const float*)d_in[17];
    const float* v3  = (const float*)d_in[18];

    char* ws = (char*)d_ws;
    float* h    = (float*)(ws);                  // 134,217,728 B
    int*   idxb = (int*)(ws + 134217728);        //     524,288 B
    float* sc   = (float*)(ws + 134742016);      //       1,792 B
    float* w3t  = (float*)(ws + 134744064);      //     131,072 B
    float* h2g  = (float*)d_out;                 // 67,108,864 B scratch (dead until gather)

    scales_kernel<<<1, 448, 0, stream>>>(g1, v1, g2, v2, g3, v3, sc);
    w3t_kernel<<<128, 256, 0, stream>>>(w3, w3t);
    mlp12_kernel<<<2048, 256, 0, stream>>>(x, w1, b1, m1, be1,
                                           w2, b2, m2, be2, sc, h2g);
    mlp3_kernel<<<8192, 256, 0, stream>>>(h2g, w3t, b3, m3, be3, sc, h);
    topk_kernel<<<2048, 256, 0, stream>>>(h, idxb);
    gather_kernel<<<1024, 256, 0, stream>>>(h, idxb, (float*)d_out);
}